// Round 1
// baseline (904.150 us; speedup 1.0000x reference)
//
#include <hip/hip_runtime.h>

// GNN_17575006175684: 3-layer GCN + mean-pool + linear head + log_softmax.
// Inputs (fp32 unless noted): x[N,5], src[E] i32, dst[E] i32, batch[N] i32,
// W1[5,16], b1[16], W2[16,32], b2[32], W3[32,64], b3[64], Wfc[64,2], bfc[2].
// Output: log_softmax logits [G=1024, 2] fp32.

#define BLK 256

__global__ void deg_kernel(const int* __restrict__ dst, float* __restrict__ deg, int E) {
    int i = blockIdx.x * blockDim.x + threadIdx.x;
    if (i < E) atomicAdd(&deg[dst[i]], 1.0f);
}

__global__ void dinv_kernel(float* __restrict__ deg, int N) {
    int i = blockIdx.x * blockDim.x + threadIdx.x;
    if (i < N) deg[i] = rsqrtf(deg[i] + 1.0f);   // deg^-1/2 incl. self-loop
}

// h[node,f] = sum_k in[node,k] * W[k,f]
template <int FIN, int FOUT>
__global__ void matmul_kernel(const float* __restrict__ in, const float* __restrict__ W,
                              float* __restrict__ h, int N) {
    int idx = blockIdx.x * blockDim.x + threadIdx.x;
    if (idx >= N * FOUT) return;
    int node = idx / FOUT;
    int f    = idx % FOUT;   // FOUT pow2 -> and/shift
    float acc = 0.f;
    const float* row = in + node * FIN;
#pragma unroll
    for (int k = 0; k < FIN; ++k)
        acc = fmaf(row[k], W[k * FOUT + f], acc);
    h[idx] = acc;
}

// agg[dst,f] += h[src,f] * dinv[src] * dinv[dst]
template <int F>
__global__ void scatter_kernel(const int* __restrict__ src, const int* __restrict__ dst,
                               const float* __restrict__ dinv, const float* __restrict__ h,
                               float* __restrict__ agg, int E) {
    int idx = blockIdx.x * blockDim.x + threadIdx.x;
    if (idx >= E * F) return;
    int e = idx / F;
    int f = idx % F;
    int s = src[e], d = dst[e];
    float norm = dinv[s] * dinv[d];
    atomicAdd(&agg[d * F + f], h[s * F + f] * norm);
}

// out = relu(agg + h * dinv^2 + b)   (in-place on agg is fine)
template <int F>
__global__ void finalize_kernel(float* __restrict__ agg, const float* __restrict__ h,
                                const float* __restrict__ dinv, const float* __restrict__ b,
                                int N) {
    int idx = blockIdx.x * blockDim.x + threadIdx.x;
    if (idx >= N * F) return;
    int node = idx / F;
    int f    = idx % F;
    float di = dinv[node];
    float v = agg[idx] + h[idx] * di * di + b[f];
    agg[idx] = fmaxf(v, 0.f);
}

__global__ void pool_kernel(const float* __restrict__ h, const int* __restrict__ batch,
                            float* __restrict__ pooled, float* __restrict__ counts, int N) {
    int idx = blockIdx.x * blockDim.x + threadIdx.x;
    if (idx >= N * 64) return;
    int node = idx >> 6;
    int f    = idx & 63;
    int g = batch[node];
    atomicAdd(&pooled[g * 64 + f], h[idx]);
    if (f == 0) atomicAdd(&counts[g], 1.0f);
}

__global__ void head_kernel(const float* __restrict__ pooled, const float* __restrict__ counts,
                            const float* __restrict__ Wfc, const float* __restrict__ bfc,
                            float* __restrict__ out, int G) {
    int g = blockIdx.x * blockDim.x + threadIdx.x;
    if (g >= G) return;
    float inv = 1.0f / fmaxf(counts[g], 1.0f);
    float l0 = bfc[0], l1 = bfc[1];
    const float* p = pooled + g * 64;
#pragma unroll
    for (int k = 0; k < 64; ++k) {
        float v = p[k] * inv;
        l0 = fmaf(v, Wfc[k * 2 + 0], l0);
        l1 = fmaf(v, Wfc[k * 2 + 1], l1);
    }
    float m   = fmaxf(l0, l1);
    float lse = m + logf(expf(l0 - m) + expf(l1 - m));
    out[g * 2 + 0] = l0 - lse;
    out[g * 2 + 1] = l1 - lse;
}

extern "C" void kernel_launch(void* const* d_in, const int* in_sizes, int n_in,
                              void* d_out, int out_size, void* d_ws, size_t ws_size,
                              hipStream_t stream) {
    const float* x     = (const float*)d_in[0];
    const int*   src   = (const int*)d_in[1];
    const int*   dst   = (const int*)d_in[2];
    const int*   batch = (const int*)d_in[3];
    const float* W1    = (const float*)d_in[4];
    const float* b1    = (const float*)d_in[5];
    const float* W2    = (const float*)d_in[6];
    const float* b2    = (const float*)d_in[7];
    const float* W3    = (const float*)d_in[8];
    const float* b3    = (const float*)d_in[9];
    const float* Wfc   = (const float*)d_in[10];
    const float* bfc   = (const float*)d_in[11];
    float* out = (float*)d_out;

    const int N = in_sizes[0] / 5;   // 100000
    const int E = in_sizes[1];       // 1600000
    const int G = out_size / 2;      // 1024

    // workspace layout (floats)
    float* dinv   = (float*)d_ws;                 // N
    float* bufA   = dinv + N;                     // N*64  (h)
    float* bufB   = bufA + (size_t)N * 64;        // N*64  (agg / layer out)
    float* pooled = bufB + (size_t)N * 64;        // G*64
    float* counts = pooled + (size_t)G * 64;      // G

    auto blocks = [](long n) { return (int)((n + BLK - 1) / BLK); };

    // deg / dinv (shared across all 3 layers)
    hipMemsetAsync(dinv, 0, N * sizeof(float), stream);
    deg_kernel<<<blocks(E), BLK, 0, stream>>>(dst, dinv, E);
    dinv_kernel<<<blocks(N), BLK, 0, stream>>>(dinv, N);

    // ---- layer 1: x[N,5] -> bufB[N,16] ----
    matmul_kernel<5, 16><<<blocks((long)N * 16), BLK, 0, stream>>>(x, W1, bufA, N);
    hipMemsetAsync(bufB, 0, (size_t)N * 16 * sizeof(float), stream);
    scatter_kernel<16><<<blocks((long)E * 16), BLK, 0, stream>>>(src, dst, dinv, bufA, bufB, E);
    finalize_kernel<16><<<blocks((long)N * 16), BLK, 0, stream>>>(bufB, bufA, dinv, b1, N);

    // ---- layer 2: bufB[N,16] -> bufB[N,32] ----
    matmul_kernel<16, 32><<<blocks((long)N * 32), BLK, 0, stream>>>(bufB, W2, bufA, N);
    hipMemsetAsync(bufB, 0, (size_t)N * 32 * sizeof(float), stream);
    scatter_kernel<32><<<blocks((long)E * 32), BLK, 0, stream>>>(src, dst, dinv, bufA, bufB, E);
    finalize_kernel<32><<<blocks((long)N * 32), BLK, 0, stream>>>(bufB, bufA, dinv, b2, N);

    // ---- layer 3: bufB[N,32] -> bufB[N,64] ----
    matmul_kernel<32, 64><<<blocks((long)N * 64), BLK, 0, stream>>>(bufB, W3, bufA, N);
    hipMemsetAsync(bufB, 0, (size_t)N * 64 * sizeof(float), stream);
    scatter_kernel<64><<<blocks((long)E * 64), BLK, 0, stream>>>(src, dst, dinv, bufA, bufB, E);
    finalize_kernel<64><<<blocks((long)N * 64), BLK, 0, stream>>>(bufB, bufA, dinv, b3, N);

    // ---- mean pool + head ----
    hipMemsetAsync(pooled, 0, ((size_t)G * 64 + G) * sizeof(float), stream);
    pool_kernel<<<blocks((long)N * 64), BLK, 0, stream>>>(bufB, batch, pooled, counts, N);
    head_kernel<<<blocks(G), BLK, 0, stream>>>(pooled, counts, Wfc, bfc, out, G);
}

// Round 2
// 495.300 us; speedup vs baseline: 1.8255x; 1.8255x over previous
//
#include <hip/hip_runtime.h>

// GNN_17575006175684: 3-layer GCN + mean-pool + linear head + log_softmax.
// R2: aggregate-before-transform (A(XW)=(AX)W), CSR-by-dst gather (no float
// atomics), prescale Xs=dinv*X so A_hat X = dinv*(A*Xs + Xs), fused matmul
// epilogue (dinv, bias, relu, next-layer prescale).

#define BLK 256

// ---------------- CSR build ----------------

__global__ void deg_hist_kernel(const int* __restrict__ dst, int* __restrict__ deg, int E) {
    int i = blockIdx.x * blockDim.x + threadIdx.x;
    if (i < E) atomicAdd(&deg[dst[i]], 1);
}

__global__ void dinv_kernel(const int* __restrict__ deg, float* __restrict__ dinv, int N) {
    int i = blockIdx.x * blockDim.x + threadIdx.x;
    if (i < N) dinv[i] = rsqrtf((float)deg[i] + 1.0f);   // +1 self-loop
}

__global__ void scan1_kernel(const int* __restrict__ deg, int* __restrict__ row_local,
                             int* __restrict__ partials, int N) {
    __shared__ int sdata[256];
    int base = blockIdx.x * 1024;
    int t = threadIdx.x;
    int v[4];
    int sum = 0;
#pragma unroll
    for (int j = 0; j < 4; ++j) {
        int i = base + t * 4 + j;
        v[j] = (i < N) ? deg[i] : 0;
        sum += v[j];
    }
    sdata[t] = sum;
    __syncthreads();
    for (int off = 1; off < 256; off <<= 1) {
        int x = (t >= off) ? sdata[t - off] : 0;
        __syncthreads();
        if (t >= off) sdata[t] += x;
        __syncthreads();
    }
    int excl = sdata[t] - sum;
    if (t == 255) partials[blockIdx.x] = sdata[255];
    int run = excl;
#pragma unroll
    for (int j = 0; j < 4; ++j) {
        int i = base + t * 4 + j;
        if (i < N) { row_local[i] = run; run += v[j]; }
    }
}

__global__ void scan2_kernel(int* __restrict__ partials, int nb) {
    __shared__ int sdata[256];
    int t = threadIdx.x;
    int v = (t < nb) ? partials[t] : 0;
    sdata[t] = v;
    __syncthreads();
    for (int off = 1; off < 256; off <<= 1) {
        int x = (t >= off) ? sdata[t - off] : 0;
        __syncthreads();
        if (t >= off) sdata[t] += x;
        __syncthreads();
    }
    if (t < nb) partials[t] = sdata[t] - v;   // exclusive
}

__global__ void scan3_kernel(int* __restrict__ row_ptr, const int* __restrict__ partials,
                             int* __restrict__ cursor, int N, int E) {
    int i = blockIdx.x * blockDim.x + threadIdx.x;
    if (i < N) {
        int v = row_ptr[i] + partials[i >> 10];
        row_ptr[i] = v;
        cursor[i] = v;
    }
    if (i == 0) row_ptr[N] = E;
}

__global__ void fill_kernel(const int* __restrict__ src, const int* __restrict__ dst,
                            int* __restrict__ cursor, int* __restrict__ col, int E) {
    int e = blockIdx.x * blockDim.x + threadIdx.x;
    if (e < E) {
        int p = atomicAdd(&cursor[dst[e]], 1);
        col[p] = src[e];
    }
}

// ---------------- layers ----------------

__global__ void prescale1_kernel(const float* __restrict__ x, const float* __restrict__ dinv,
                                 float* __restrict__ xs, int N) {
    int idx = blockIdx.x * blockDim.x + threadIdx.x;
    if (idx >= N * 5) return;
    int n = idx / 5;
    xs[idx] = x[idx] * dinv[n];
}

template <int F>
__global__ void gather_kernel(const int* __restrict__ row_ptr, const int* __restrict__ col,
                              const float* __restrict__ xs, float* __restrict__ g, int N) {
    int idx = blockIdx.x * blockDim.x + threadIdx.x;
    if (idx >= N * F) return;
    int n = idx / F, f = idx % F;
    int beg = row_ptr[n], end = row_ptr[n + 1];
    float acc = xs[idx];
    int e = beg;
    for (; e + 3 < end; e += 4) {
        int s0 = col[e], s1 = col[e + 1], s2 = col[e + 2], s3 = col[e + 3];
        float a = xs[s0 * F + f], b = xs[s1 * F + f];
        float c = xs[s2 * F + f], d = xs[s3 * F + f];
        acc += a + b + c + d;
    }
    for (; e < end; ++e) acc += xs[col[e] * F + f];
    g[idx] = acc;
}

template <int F>
__global__ void gather4_kernel(const int* __restrict__ row_ptr, const int* __restrict__ col,
                               const float4* __restrict__ xs, float4* __restrict__ g, int N) {
    constexpr int FQ = F / 4;
    int idx = blockIdx.x * blockDim.x + threadIdx.x;
    if (idx >= N * FQ) return;
    int n = idx / FQ, q = idx % FQ;
    int beg = row_ptr[n], end = row_ptr[n + 1];
    float4 acc = xs[n * FQ + q];
    int e = beg;
    for (; e + 3 < end; e += 4) {
        int s0 = col[e], s1 = col[e + 1], s2 = col[e + 2], s3 = col[e + 3];
        float4 a = xs[s0 * FQ + q];
        float4 b = xs[s1 * FQ + q];
        float4 c = xs[s2 * FQ + q];
        float4 d = xs[s3 * FQ + q];
        acc.x += a.x + b.x + c.x + d.x;
        acc.y += a.y + b.y + c.y + d.y;
        acc.z += a.z + b.z + c.z + d.z;
        acc.w += a.w + b.w + c.w + d.w;
    }
    for (; e < end; ++e) {
        float4 a = xs[col[e] * FQ + q];
        acc.x += a.x; acc.y += a.y; acc.z += a.z; acc.w += a.w;
    }
    g[n * FQ + q] = acc;
}

template <int FIN, int FOUT, bool PRESCALE_OUT>
__global__ void matmul_kernel(const float* __restrict__ g, const float* __restrict__ W,
                              const float* __restrict__ b, const float* __restrict__ dinv,
                              float* __restrict__ out, int N) {
    int idx = blockIdx.x * blockDim.x + threadIdx.x;
    if (idx >= N * FOUT) return;
    int n = idx / FOUT, f = idx % FOUT;
    float di = dinv[n];
    float acc = 0.f;
    const float* row = g + n * FIN;
#pragma unroll
    for (int k = 0; k < FIN; ++k)
        acc = fmaf(row[k], W[k * FOUT + f], acc);
    float v = fmaxf(di * acc + b[f], 0.f);
    out[idx] = PRESCALE_OUT ? v * di : v;
}

// ---------------- pool + head ----------------

__global__ void pool_kernel(const float* __restrict__ h, const int* __restrict__ batch,
                            float* __restrict__ pooled, float* __restrict__ counts, int N) {
    int idx = blockIdx.x * blockDim.x + threadIdx.x;
    if (idx >= N * 64) return;
    int node = idx >> 6;
    int f    = idx & 63;
    int gph = batch[node];
    atomicAdd(&pooled[gph * 64 + f], h[idx]);
    if (f == 0) atomicAdd(&counts[gph], 1.0f);
}

__global__ void head_kernel(const float* __restrict__ pooled, const float* __restrict__ counts,
                            const float* __restrict__ Wfc, const float* __restrict__ bfc,
                            float* __restrict__ out, int G) {
    int gph = blockIdx.x * blockDim.x + threadIdx.x;
    if (gph >= G) return;
    float inv = 1.0f / fmaxf(counts[gph], 1.0f);
    float l0 = bfc[0], l1 = bfc[1];
    const float* p = pooled + gph * 64;
#pragma unroll
    for (int k = 0; k < 64; ++k) {
        float v = p[k] * inv;
        l0 = fmaf(v, Wfc[k * 2 + 0], l0);
        l1 = fmaf(v, Wfc[k * 2 + 1], l1);
    }
    float m   = fmaxf(l0, l1);
    float lse = m + logf(expf(l0 - m) + expf(l1 - m));
    out[gph * 2 + 0] = l0 - lse;
    out[gph * 2 + 1] = l1 - lse;
}

// ---------------- driver ----------------

extern "C" void kernel_launch(void* const* d_in, const int* in_sizes, int n_in,
                              void* d_out, int out_size, void* d_ws, size_t ws_size,
                              hipStream_t stream) {
    const float* x     = (const float*)d_in[0];
    const int*   src   = (const int*)d_in[1];
    const int*   dst   = (const int*)d_in[2];
    const int*   batch = (const int*)d_in[3];
    const float* W1    = (const float*)d_in[4];
    const float* b1    = (const float*)d_in[5];
    const float* W2    = (const float*)d_in[6];
    const float* b2    = (const float*)d_in[7];
    const float* W3    = (const float*)d_in[8];
    const float* b3    = (const float*)d_in[9];
    const float* Wfc   = (const float*)d_in[10];
    const float* bfc   = (const float*)d_in[11];
    float* out = (float*)d_out;

    const int N = in_sizes[0] / 5;   // 100000
    const int E = in_sizes[1];       // 1600000
    const int G = out_size / 2;      // 1024

    // workspace layout (4B units; all region sizes multiples of 4 -> 16B aligned)
    int* deg      = (int*)d_ws;                   // N
    int* row_ptr  = deg + N;                      // N+4 (uses N+1)
    int* cursor   = row_ptr + N + 4;              // N
    int* col      = cursor + N;                   // E
    int* partials = col + E;                      // 512
    float* dinv   = (float*)(partials + 512);     // N
    float* A      = dinv + N;                     // N*64
    float* B      = A + (size_t)N * 64;           // N*64
    float* pooled = B + (size_t)N * 64;           // G*64
    float* counts = pooled + (size_t)G * 64;      // G
    // total ~ 66 MB

    auto blocks = [](long n) { return (int)((n + BLK - 1) / BLK); };
    const int nb_scan = (N + 1023) / 1024;        // <=256

    // ---- CSR build (by dst) + dinv ----
    hipMemsetAsync(deg, 0, N * sizeof(int), stream);
    deg_hist_kernel<<<blocks(E), BLK, 0, stream>>>(dst, deg, E);
    dinv_kernel<<<blocks(N), BLK, 0, stream>>>(deg, dinv, N);
    scan1_kernel<<<nb_scan, 256, 0, stream>>>(deg, row_ptr, partials, N);
    scan2_kernel<<<1, 256, 0, stream>>>(partials, nb_scan);
    scan3_kernel<<<blocks(N), BLK, 0, stream>>>(row_ptr, partials, cursor, N, E);
    fill_kernel<<<blocks(E), BLK, 0, stream>>>(src, dst, cursor, col, E);

    // ---- layer 1: x[N,5] -> Xs2 in B[N,16] ----
    prescale1_kernel<<<blocks((long)N * 5), BLK, 0, stream>>>(x, dinv, B, N);              // B = Xs1 [N,5]
    gather_kernel<5><<<blocks((long)N * 5), BLK, 0, stream>>>(row_ptr, col, B, A, N);      // A = g1  [N,5]
    matmul_kernel<5, 16, true><<<blocks((long)N * 16), BLK, 0, stream>>>(A, W1, b1, dinv, B, N);  // B = Xs2 [N,16]

    // ---- layer 2: B[N,16] -> Xs3 in B[N,32] ----
    gather4_kernel<16><<<blocks((long)N * 4), BLK, 0, stream>>>(row_ptr, col,
        (const float4*)B, (float4*)A, N);                                                  // A = g2 [N,16]
    matmul_kernel<16, 32, true><<<blocks((long)N * 32), BLK, 0, stream>>>(A, W2, b2, dinv, B, N); // B = Xs3 [N,32]

    // ---- layer 3: B[N,32] -> out3 in B[N,64] (via A) ----
    gather4_kernel<32><<<blocks((long)N * 8), BLK, 0, stream>>>(row_ptr, col,
        (const float4*)B, (float4*)A, N);                                                  // A = g3 [N,32]
    matmul_kernel<32, 64, false><<<blocks((long)N * 64), BLK, 0, stream>>>(A, W3, b3, dinv, B, N); // B = out3 [N,64]

    // ---- mean pool + head ----
    hipMemsetAsync(pooled, 0, ((size_t)G * 64 + G) * sizeof(float), stream);
    pool_kernel<<<blocks((long)N * 64), BLK, 0, stream>>>(B, batch, pooled, counts, N);
    head_kernel<<<blocks(G), BLK, 0, stream>>>(pooled, counts, Wfc, bfc, out, G);
}

// Round 3
// 339.245 us; speedup vs baseline: 2.6652x; 1.4600x over previous
//
#include <hip/hip_runtime.h>

// GNN_17575006175684: 3-layer GCN + mean-pool + linear head + log_softmax.
// R3: XCD-sliced deg-histogram + CSR fill (atomics/stores confined to one
// 0.8MB dst-slice per XCD -> L2-local, no cross-XCD line bounce, no 64B
// write amplification); atomic-free pool+head via sorted-batch binary-search
// boundaries + block-per-graph coalesced reduction.

#define BLK 256
#define NSLICE 8   // XCDs on MI355X; blockIdx%8 -> XCD is a locality heuristic only

// ---------------- CSR build ----------------

__global__ void deg_hist_sliced(const int* __restrict__ dst, int* __restrict__ deg,
                                int E, int sliceSz) {
    int slice = blockIdx.x & (NSLICE - 1);
    int cid   = blockIdx.x >> 3;
    int nch   = gridDim.x >> 3;
    int lo = slice * sliceSz, hi = lo + sliceSz;
    for (int e = cid * blockDim.x + threadIdx.x; e < E; e += nch * blockDim.x) {
        int d = dst[e];
        if (d >= lo && d < hi) atomicAdd(&deg[d], 1);
    }
}

__global__ void dinv_kernel(const int* __restrict__ deg, float* __restrict__ dinv, int N) {
    int i = blockIdx.x * blockDim.x + threadIdx.x;
    if (i < N) dinv[i] = rsqrtf((float)deg[i] + 1.0f);   // +1 self-loop
}

__global__ void scan1_kernel(const int* __restrict__ deg, int* __restrict__ row_local,
                             int* __restrict__ partials, int N) {
    __shared__ int sdata[256];
    int base = blockIdx.x * 1024;
    int t = threadIdx.x;
    int v[4];
    int sum = 0;
#pragma unroll
    for (int j = 0; j < 4; ++j) {
        int i = base + t * 4 + j;
        v[j] = (i < N) ? deg[i] : 0;
        sum += v[j];
    }
    sdata[t] = sum;
    __syncthreads();
    for (int off = 1; off < 256; off <<= 1) {
        int x = (t >= off) ? sdata[t - off] : 0;
        __syncthreads();
        if (t >= off) sdata[t] += x;
        __syncthreads();
    }
    int excl = sdata[t] - sum;
    if (t == 255) partials[blockIdx.x] = sdata[255];
    int run = excl;
#pragma unroll
    for (int j = 0; j < 4; ++j) {
        int i = base + t * 4 + j;
        if (i < N) { row_local[i] = run; run += v[j]; }
    }
}

__global__ void scan2_kernel(int* __restrict__ partials, int nb) {
    __shared__ int sdata[256];
    int t = threadIdx.x;
    int v = (t < nb) ? partials[t] : 0;
    sdata[t] = v;
    __syncthreads();
    for (int off = 1; off < 256; off <<= 1) {
        int x = (t >= off) ? sdata[t - off] : 0;
        __syncthreads();
        if (t >= off) sdata[t] += x;
        __syncthreads();
    }
    if (t < nb) partials[t] = sdata[t] - v;   // exclusive
}

__global__ void scan3_kernel(int* __restrict__ row_ptr, const int* __restrict__ partials,
                             int* __restrict__ cursor, int N, int E) {
    int i = blockIdx.x * blockDim.x + threadIdx.x;
    if (i < N) {
        int v = row_ptr[i] + partials[i >> 10];
        row_ptr[i] = v;
        cursor[i] = v;
    }
    if (i == 0) row_ptr[N] = E;
}

__global__ void fill_sliced(const int* __restrict__ src, const int* __restrict__ dst,
                            int* __restrict__ cursor, int* __restrict__ col,
                            int E, int sliceSz) {
    int slice = blockIdx.x & (NSLICE - 1);
    int cid   = blockIdx.x >> 3;
    int nch   = gridDim.x >> 3;
    int lo = slice * sliceSz, hi = lo + sliceSz;
    for (int e = cid * blockDim.x + threadIdx.x; e < E; e += nch * blockDim.x) {
        int d = dst[e];
        if (d >= lo && d < hi) {
            int p = atomicAdd(&cursor[d], 1);
            col[p] = src[e];
        }
    }
}

// ---------------- layers ----------------

__global__ void prescale1_kernel(const float* __restrict__ x, const float* __restrict__ dinv,
                                 float* __restrict__ xs, int N) {
    int idx = blockIdx.x * blockDim.x + threadIdx.x;
    if (idx >= N * 5) return;
    int n = idx / 5;
    xs[idx] = x[idx] * dinv[n];
}

template <int F>
__global__ void gather_kernel(const int* __restrict__ row_ptr, const int* __restrict__ col,
                              const float* __restrict__ xs, float* __restrict__ g, int N) {
    int idx = blockIdx.x * blockDim.x + threadIdx.x;
    if (idx >= N * F) return;
    int n = idx / F, f = idx % F;
    int beg = row_ptr[n], end = row_ptr[n + 1];
    float acc = xs[idx];
    int e = beg;
    for (; e + 3 < end; e += 4) {
        int s0 = col[e], s1 = col[e + 1], s2 = col[e + 2], s3 = col[e + 3];
        float a = xs[s0 * F + f], b = xs[s1 * F + f];
        float c = xs[s2 * F + f], d = xs[s3 * F + f];
        acc += a + b + c + d;
    }
    for (; e < end; ++e) acc += xs[col[e] * F + f];
    g[idx] = acc;
}

template <int F>
__global__ void gather4_kernel(const int* __restrict__ row_ptr, const int* __restrict__ col,
                               const float4* __restrict__ xs, float4* __restrict__ g, int N) {
    constexpr int FQ = F / 4;
    int idx = blockIdx.x * blockDim.x + threadIdx.x;
    if (idx >= N * FQ) return;
    int n = idx / FQ, q = idx % FQ;
    int beg = row_ptr[n], end = row_ptr[n + 1];
    float4 acc = xs[n * FQ + q];
    int e = beg;
    for (; e + 3 < end; e += 4) {
        int s0 = col[e], s1 = col[e + 1], s2 = col[e + 2], s3 = col[e + 3];
        float4 a = xs[s0 * FQ + q];
        float4 b = xs[s1 * FQ + q];
        float4 c = xs[s2 * FQ + q];
        float4 d = xs[s3 * FQ + q];
        acc.x += a.x + b.x + c.x + d.x;
        acc.y += a.y + b.y + c.y + d.y;
        acc.z += a.z + b.z + c.z + d.z;
        acc.w += a.w + b.w + c.w + d.w;
    }
    for (; e < end; ++e) {
        float4 a = xs[col[e] * FQ + q];
        acc.x += a.x; acc.y += a.y; acc.z += a.z; acc.w += a.w;
    }
    g[n * FQ + q] = acc;
}

template <int FIN, int FOUT, bool PRESCALE_OUT>
__global__ void matmul_kernel(const float* __restrict__ g, const float* __restrict__ W,
                              const float* __restrict__ b, const float* __restrict__ dinv,
                              float* __restrict__ out, int N) {
    int idx = blockIdx.x * blockDim.x + threadIdx.x;
    if (idx >= N * FOUT) return;
    int n = idx / FOUT, f = idx % FOUT;
    float di = dinv[n];
    float acc = 0.f;
    const float* row = g + n * FIN;
#pragma unroll
    for (int k = 0; k < FIN; ++k)
        acc = fmaf(row[k], W[k * FOUT + f], acc);
    float v = fmaxf(di * acc + b[f], 0.f);
    out[idx] = PRESCALE_OUT ? v * di : v;
}

// ---------------- pool + head (atomic-free) ----------------

// start[g] = first index i with batch[i] >= g (batch sorted); start[G] = N
__global__ void bounds_kernel(const int* __restrict__ batch, int* __restrict__ start,
                              int N, int G) {
    int g = blockIdx.x * blockDim.x + threadIdx.x;
    if (g > G) return;
    if (g == G) { start[G] = N; return; }
    int lo = 0, hi = N;
    while (lo < hi) {
        int mid = (lo + hi) >> 1;
        if (batch[mid] < g) lo = mid + 1; else hi = mid;
    }
    start[g] = lo;
}

// one block (4 waves) per graph: segmented mean over h[start..end), then
// 64x2 matvec + log_softmax
__global__ void pool_head_kernel(const float* __restrict__ h, const int* __restrict__ start,
                                 const float* __restrict__ Wfc, const float* __restrict__ bfc,
                                 float* __restrict__ out) {
    __shared__ float part[4][64];
    int g = blockIdx.x;
    int t = threadIdx.x;          // 256
    int f = t & 63, w = t >> 6;
    int s = start[g], e = start[g + 1];
    float acc = 0.f;
    for (int n = s + w; n < e; n += 4)
        acc += h[(size_t)n * 64 + f];
    part[w][f] = acc;
    __syncthreads();
    if (w == 0) {
        float p = part[0][f] + part[1][f] + part[2][f] + part[3][f];
        p /= fmaxf((float)(e - s), 1.0f);
        float l0 = p * Wfc[f * 2 + 0];
        float l1 = p * Wfc[f * 2 + 1];
#pragma unroll
        for (int off = 32; off; off >>= 1) {
            l0 += __shfl_down(l0, off);
            l1 += __shfl_down(l1, off);
        }
        if (f == 0) {
            l0 += bfc[0]; l1 += bfc[1];
            float m   = fmaxf(l0, l1);
            float lse = m + logf(expf(l0 - m) + expf(l1 - m));
            out[g * 2 + 0] = l0 - lse;
            out[g * 2 + 1] = l1 - lse;
        }
    }
}

// ---------------- driver ----------------

extern "C" void kernel_launch(void* const* d_in, const int* in_sizes, int n_in,
                              void* d_out, int out_size, void* d_ws, size_t ws_size,
                              hipStream_t stream) {
    const float* x     = (const float*)d_in[0];
    const int*   src   = (const int*)d_in[1];
    const int*   dst   = (const int*)d_in[2];
    const int*   batch = (const int*)d_in[3];
    const float* W1    = (const float*)d_in[4];
    const float* b1    = (const float*)d_in[5];
    const float* W2    = (const float*)d_in[6];
    const float* b2    = (const float*)d_in[7];
    const float* W3    = (const float*)d_in[8];
    const float* b3    = (const float*)d_in[9];
    const float* Wfc   = (const float*)d_in[10];
    const float* bfc   = (const float*)d_in[11];
    float* out = (float*)d_out;

    const int N = in_sizes[0] / 5;   // 100000
    const int E = in_sizes[1];       // 1600000
    const int G = out_size / 2;      // 1024

    // workspace layout (4B units; region sizes multiples of 4 -> 16B aligned)
    int* deg      = (int*)d_ws;                   // N
    int* row_ptr  = deg + N;                      // N+4 (uses N+1)
    int* cursor   = row_ptr + N + 4;              // N
    int* col      = cursor + N;                   // E
    int* partials = col + E;                      // 512
    int* start    = partials + 512;               // G+8 (uses G+1)
    float* dinv   = (float*)(start + G + 8);      // N
    float* A      = dinv + N;                     // N*64
    float* B      = A + (size_t)N * 64;           // N*64
    // total ~ 66 MB

    auto blocks = [](long n) { return (int)((n + BLK - 1) / BLK); };
    const int nb_scan  = (N + 1023) / 1024;       // <=256
    const int sliceSz  = (N + NSLICE - 1) / NSLICE;
    const int gridSl   = 256 * NSLICE;            // 2048 blocks, 256 chunks/slice

    // ---- CSR build (by dst) + dinv ----
    hipMemsetAsync(deg, 0, N * sizeof(int), stream);
    deg_hist_sliced<<<gridSl, BLK, 0, stream>>>(dst, deg, E, sliceSz);
    dinv_kernel<<<blocks(N), BLK, 0, stream>>>(deg, dinv, N);
    scan1_kernel<<<nb_scan, 256, 0, stream>>>(deg, row_ptr, partials, N);
    scan2_kernel<<<1, 256, 0, stream>>>(partials, nb_scan);
    scan3_kernel<<<blocks(N), BLK, 0, stream>>>(row_ptr, partials, cursor, N, E);
    fill_sliced<<<gridSl, BLK, 0, stream>>>(src, dst, cursor, col, E, sliceSz);

    // ---- pool boundaries (independent; overlaps nothing but cheap) ----
    bounds_kernel<<<blocks(G + 1), BLK, 0, stream>>>(batch, start, N, G);

    // ---- layer 1: x[N,5] -> Xs2 in B[N,16] ----
    prescale1_kernel<<<blocks((long)N * 5), BLK, 0, stream>>>(x, dinv, B, N);              // B = Xs1 [N,5]
    gather_kernel<5><<<blocks((long)N * 5), BLK, 0, stream>>>(row_ptr, col, B, A, N);      // A = g1  [N,5]
    matmul_kernel<5, 16, true><<<blocks((long)N * 16), BLK, 0, stream>>>(A, W1, b1, dinv, B, N);  // B = Xs2 [N,16]

    // ---- layer 2: B[N,16] -> Xs3 in B[N,32] ----
    gather4_kernel<16><<<blocks((long)N * 4), BLK, 0, stream>>>(row_ptr, col,
        (const float4*)B, (float4*)A, N);                                                  // A = g2 [N,16]
    matmul_kernel<16, 32, true><<<blocks((long)N * 32), BLK, 0, stream>>>(A, W2, b2, dinv, B, N); // B = Xs3 [N,32]

    // ---- layer 3: B[N,32] -> out3 in B[N,64] (via A) ----
    gather4_kernel<32><<<blocks((long)N * 8), BLK, 0, stream>>>(row_ptr, col,
        (const float4*)B, (float4*)A, N);                                                  // A = g3 [N,32]
    matmul_kernel<32, 64, false><<<blocks((long)N * 64), BLK, 0, stream>>>(A, W3, b3, dinv, B, N); // B = out3 [N,64]

    // ---- mean pool + head (no atomics) ----
    pool_head_kernel<<<G, 256, 0, stream>>>(B, start, Wfc, bfc, out);
}